// Round 13
// baseline (208.557 us; speedup 1.0000x reference)
//
#include <hip/hip_runtime.h>
#include <math.h>

#define HID 64
#define FD 32
#define ROWP 128   // LDS row pitch bytes; XOR swizzle ((c15&7)<<4) kills conflicts

typedef __fp16 f16x8 __attribute__((ext_vector_type(8)));
typedef __fp16 f16x2v __attribute__((ext_vector_type(2)));
typedef float  f32x4 __attribute__((ext_vector_type(4)));
typedef unsigned int u32x4 __attribute__((ext_vector_type(4)));
typedef unsigned int u32x2 __attribute__((ext_vector_type(2)));

__device__ __forceinline__ unsigned int pk2(float a, float b) {
    auto v = __builtin_amdgcn_cvt_pkrtz(a, b);
    return __builtin_bit_cast(unsigned int, v);
}
__device__ __forceinline__ unsigned int pkadd(unsigned int a, unsigned int b) {
    f16x2v x = __builtin_bit_cast(f16x2v, a), y = __builtin_bit_cast(f16x2v, b);
    f16x2v r = x + y;
    return __builtin_bit_cast(unsigned int, r);
}
__device__ __forceinline__ unsigned int pkmax0(unsigned int a) {
    f16x2v x = __builtin_bit_cast(f16x2v, a);
    f16x2v z = {(__fp16)0.f, (__fp16)0.f};
    f16x2v r = __builtin_elementwise_max(x, z);
    return __builtin_bit_cast(unsigned int, r);
}
__device__ __forceinline__ f32x4 mfma16(f16x8 a, f16x8 b, f32x4 c) {
    return __builtin_amdgcn_mfma_f32_16x16x32_f16(a, b, c, 0, 0, 0);
}

// t-schedule matched to numpy (f64 linspace; correctly-rounded exp). Prep-only.
__device__ __forceinline__ float t_of(int i) {
    #pragma clang fp contract(off)
    if (i < 64) {
        if (i == 63) return 1.1f;
        return (float)(0.1 + (double)i * (1.0 / 63.0));
    }
    const float LOGC = 0.0038986404159402954f;
    float arg = (float)(i - 64) * LOGC;
    return (float)exp((double)arg) * 1.1f;
}

// ws layout (bytes): identical to round 12
//   [0,20480)      : 20 A-frags x 64 lanes x 16B  (f16 MFMA A-layout)
//   [20480,20672)  : b2e[48] f32 = [b2 | b2.Ws+bs | 0]
//   [20672,20736)  : fpk[16]  u32 = b2 f16-pairs
//   [20736,20864)  : r1pk[32] u32 = br1 f16-pairs
//   [20864,21376)  : ttab[128] f32
//   [21376,21888)  : dtab[128] f32
__global__ void prep(const float* __restrict__ W1, const float* __restrict__ b1,
                     const float* __restrict__ W2, const float* __restrict__ b2,
                     const float* __restrict__ Ws, const float* __restrict__ bs,
                     const float* __restrict__ Wr1, const float* __restrict__ br1,
                     const float* __restrict__ Wr2,
                     unsigned char* __restrict__ wsb) {
    __shared__ float wv[64];
    const int t = threadIdx.x;                 // 1024 threads, 1 block
    if (t < 64) {
        float acc = 0.f;
        for (int k = 0; k < FD; ++k) acc = fmaf(W2[t*FD+k], Ws[k], acc);
        wv[t] = acc;
    }
    __syncthreads();
    float* b2e = (float*)(wsb + 20480);
    unsigned int* fpk  = (unsigned int*)(wsb + 20672);
    unsigned int* r1pk = (unsigned int*)(wsb + 20736);
    float* ttab = (float*)(wsb + 20864);
    float* dtab = (float*)(wsb + 21376);
    if (t < 48) {
        float v = 0.f;
        if (t < 32) v = b2[t];
        else if (t == 32) {
            float c = bs[0];
            for (int k = 0; k < FD; ++k) c = fmaf(b2[k], Ws[k], c);
            v = c;
        }
        b2e[t] = v;
    }
    if (t >= 64 && t < 192) { int s = t - 64; ttab[s] = t_of(s); dtab[s] = t_of(s+1) - t_of(s); }
    if (t >= 192 && t < 208) {
        int e = t - 192, mt = e >> 3, g = (e >> 1) & 3, p = e & 1;
        int row = 16*mt + 4*g + 2*p;
        fpk[e] = pk2(b2[row], b2[row+1]);
    }
    if (t >= 208 && t < 240) {
        int e = t - 208, mt = e >> 3, g = (e >> 1) & 3, p = e & 1;
        int row = 16*mt + 4*g + 2*p;
        r1pk[e] = pk2(br1[row], br1[row+1]);
    }
    const int f = t >> 6, lane = t & 63;
    const int c15 = lane & 15, g = lane >> 4;
    f16x8 o;
    #pragma unroll
    for (int j = 0; j < 8; ++j) {
        float v = 0.f;
        if (f < 6) {
            int mt = f >> 1, kc = f & 1, row = 16*mt + c15;
            int kg = 32*kc + 8*g + j;
            v = (row < 32) ? W2[kg*FD + row] : ((row == 32) ? wv[kg] : 0.f);
        } else if (f < 14) {
            int ff = f - 6, mt = ff >> 1, kc = ff & 1, row = 16*mt + c15;
            int kg = 32*kc + 8*g + j;
            v = (kg < FD+3) ? Wr1[kg*HID + row] : 0.f;
        } else {
            int kc = f - 14, row = c15;
            int kg = 32*kc + 8*g + j;
            v = (row < 3) ? Wr2[kg*3 + row] : 0.f;
        }
        o[j] = (__fp16)v;
    }
    *(f16x8*)(wsb + (f*64 + lane)*16) = o;
    if (f < 4) {                                // L1 A-frag 16+f (mt=f)
        f16x8 o2;
        #pragma unroll
        for (int j = 0; j < 8; ++j) {
            int row = 16*f + c15, k = 8*g + j;
            float v = 0.f;
            if (k < 3)       v = W1[k*HID + row];
            else if (k < 6)  v = W1[(k-3)*HID + row];
            else if (k == 6) v = b1[row];
            o2[j] = (__fp16)v;
        }
        *(f16x8*)(wsb + ((16+f)*64 + lane)*16) = o2;
    }
}

__device__ __forceinline__ bool gv(const float* __restrict__ g, int zi, int yi, int xi) {
    bool ok = ((unsigned)zi < 128u) & ((unsigned)yi < 128u) & ((unsigned)xi < 128u);
    int zc = min(max(zi, 0), 127);
    int yc = min(max(yi, 0), 127);
    int xc = min(max(xi, 0), 127);
    float v = g[(((zc << 7) + yc) << 7) + xc];
    return ok & (v > 0.5f);
}

__global__ __launch_bounds__(64, 5) void nerf_render(
    const float* __restrict__ rays_o, const float* __restrict__ rays_d,
    const float* __restrict__ grid,  const float* __restrict__ br2,
    const unsigned char* __restrict__ wsb,
    float* __restrict__ out)
{
    __shared__ unsigned char ldsH[8192] __attribute__((aligned(16)));  // [64][ROWP]
    const int lane = threadIdx.x;              // 1 wave per block
    const int ray  = blockIdx.x;
    const int c15 = lane & 15, g = lane >> 4;
    const int swc = (c15 & 7) << 4;            // XOR bank swizzle (row&7 == c15&7)

    const f16x8* AF = (const f16x8*)wsb;
    const float* b2e = (const float*)(wsb + 20480);
    const unsigned int* fpk  = (const unsigned int*)(wsb + 20672);
    const unsigned int* r1pk = (const unsigned int*)(wsb + 20736);
    const float* ttab = (const float*)(wsb + 20864);
    const float* dtab = (const float*)(wsb + 21376);

    const float ox = rays_o[ray*3+0], oy = rays_o[ray*3+1], oz = rays_o[ray*3+2];
    const float dx = rays_d[ray*3+0], dy = rays_d[ray*3+1], dz = rays_d[ray*3+2];

    const float b2e32 = b2e[32];
    unsigned int fpkv[2][2], r1pkv[4][2];
    #pragma unroll
    for (int mt = 0; mt < 2; ++mt) { fpkv[mt][0] = fpk[mt*8+g*2]; fpkv[mt][1] = fpk[mt*8+g*2+1]; }
    #pragma unroll
    for (int mt = 0; mt < 4; ++mt) { r1pkv[mt][0] = r1pk[mt*8+g*2]; r1pkv[mt][1] = r1pk[mt*8+g*2+1]; }
    const unsigned int p3c = pk2(1.f, 0.f);
    const float c0b = br2[0], c1b = br2[1], c2b = br2[2];

    f16x8 bd;                                   // dirs B-frag (kc=1 of color L1)
    #pragma unroll
    for (int j = 0; j < 8; ++j) bd[j] = (__fp16)0.f;
    if (g == 0) { bd[0] = (__fp16)dx; bd[1] = (__fp16)dy; bd[2] = (__fp16)dz; }

    float rr = 0.f, rg = 0.f, rb = 0.f;
    float carry = 0.f;

    #pragma unroll 1
    for (int chunk = 0; chunk < 2; ++chunk) {
        const int s  = (chunk << 6) + lane;
        const bool vs = (s < 127);
        const float tv = ttab[s];
        const float dist = dtab[s];

        float cx, cy, cz, fx, fy, fz;
        int x0, y0, z0;
        {
            #pragma clang fp contract(off)
            float px = ox + dx * tv;
            float py = oy + dy * tv;
            float pz = oz + dz * tv;
            float nrm = fmaxf(fabsf(px), fmaxf(fabsf(py), fabsf(pz)));
            if (nrm <= 1.0f) { cx = px; cy = py; cz = pz; }
            else {
                float t2 = 2.0f - 1.0f / nrm;
                cx = (t2 * px) / nrm; cy = (t2 * py) / nrm; cz = (t2 * pz) / nrm;
            }
            cx = cx * 0.5f; cy = cy * 0.5f; cz = cz * 0.5f;
            float gx = ((cx + 1.0f) * 128.0f - 1.0f) * 0.5f;
            float gy = ((cy + 1.0f) * 128.0f - 1.0f) * 0.5f;
            float gz = ((cz + 1.0f) * 128.0f - 1.0f) * 0.5f;
            float xf = floorf(gx), yf = floorf(gy), zf = floorf(gz);
            fx = gx - xf; fy = gy - yf; fz = gz - zf;
            x0 = (int)xf; y0 = (int)yf; z0 = (int)zf;
        }
        const bool fxp = fx > 0.f, fyp = fy > 0.f, fzp = fz > 0.f;
        bool m = gv(grid, z0,   y0,   x0)
             | (fxp             & gv(grid, z0,   y0,   x0+1))
             | (fyp             & gv(grid, z0,   y0+1, x0))
             | (fyp & fxp       & gv(grid, z0,   y0+1, x0+1))
             | (fzp             & gv(grid, z0+1, y0,   x0))
             | (fzp & fxp       & gv(grid, z0+1, y0,   x0+1))
             | (fzp & fyp       & gv(grid, z0+1, y0+1, x0))
             | (fzp & fyp & fxp & gv(grid, z0+1, y0+1, x0+1));
        m = m & vs;

        if (__ballot(m)) {
            // ---- coords hi/lo split (full f32 precision via MFMA) ----
            float xh = (float)(__fp16)cx, yh = (float)(__fp16)cy, zh = (float)(__fp16)cz;
            unsigned int q0 = pk2(xh, yh);
            unsigned int q1 = pk2(zh, cx - xh);
            unsigned int q2 = pk2(cy - yh, cz - zh);

            // ---- L1 via MFMA: H^T = W1e^T [c_hi;c_lo;1]^T (K=32, bias folded) ----
            f16x8 bl1[4];
            #pragma unroll
            for (int nt = 0; nt < 4; ++nt) {
                int ad = (16*nt + c15) << 2;
                u32x4 bw;
                bw[0] = (unsigned int)__builtin_amdgcn_ds_bpermute(ad, (int)q0);
                bw[1] = (unsigned int)__builtin_amdgcn_ds_bpermute(ad, (int)q1);
                bw[2] = (unsigned int)__builtin_amdgcn_ds_bpermute(ad, (int)q2);
                bw[3] = p3c;
                bl1[nt] = __builtin_bit_cast(f16x8, bw);
            }
            __builtin_amdgcn_s_setprio(1);
            #pragma unroll
            for (int mt = 0; mt < 4; ++mt) {
                f16x8 a = AF[(16+mt)*64 + lane];
                #pragma unroll
                for (int nt = 0; nt < 4; ++nt) {
                    f32x4 z = {0.f,0.f,0.f,0.f};
                    z = mfma16(a, bl1[nt], z);
                    u32x2 ww;
                    ww[0] = pkmax0(pk2(z[0], z[1]));
                    ww[1] = pkmax0(pk2(z[2], z[3]));
                    *(u32x2*)(ldsH + (16*nt + c15)*ROWP + ((32*mt + 8*g) ^ swc)) = ww;
                }
            }
            __builtin_amdgcn_s_setprio(0);
            // ---- read H^T B-fragments (swizzled) ----
            f16x8 bh[4][2];
            #pragma unroll
            for (int nt = 0; nt < 4; ++nt)
                #pragma unroll
                for (int kc = 0; kc < 2; ++kc)
                    bh[nt][kc] = *(const f16x8*)(ldsH + (16*nt + c15)*ROWP + ((64*kc + 16*g) ^ swc));

            // ---- L2: F^T = W2e^T H^T + b2e (row 32 = sigma_pre) ----
            float sq[4];
            __builtin_amdgcn_s_setprio(1);
            #pragma unroll
            for (int mt = 0; mt < 3; ++mt) {
                f16x8 a0 = AF[(mt*2+0)*64 + lane];
                f16x8 a1 = AF[(mt*2+1)*64 + lane];
                f32x4 acc[4];
                #pragma unroll
                for (int nt = 0; nt < 4; ++nt) { f32x4 z = {0.f,0.f,0.f,0.f}; acc[nt] = z; }
                #pragma unroll
                for (int nt = 0; nt < 4; ++nt) acc[nt] = mfma16(a0, bh[nt][0], acc[nt]);
                #pragma unroll
                for (int nt = 0; nt < 4; ++nt) acc[nt] = mfma16(a1, bh[nt][1], acc[nt]);
                if (mt < 2) {
                    #pragma unroll
                    for (int nt = 0; nt < 4; ++nt) {
                        u32x2 ww;
                        ww[0] = pkadd(pk2(acc[nt][0], acc[nt][1]), fpkv[mt][0]);
                        ww[1] = pkadd(pk2(acc[nt][2], acc[nt][3]), fpkv[mt][1]);
                        *(u32x2*)(ldsH + (16*nt + c15)*ROWP + ((32*mt + 8*g) ^ swc)) = ww;
                    }
                } else {
                    #pragma unroll
                    for (int nt = 0; nt < 4; ++nt) sq[nt] = acc[nt][0] + b2e32;
                }
            }
            __builtin_amdgcn_s_setprio(0);
            // sigma broadcast: value for col s lives in lane s&15, acc-tile s>>4
            const float sg0 = __shfl(sq[0], c15, 64);
            const float sg1 = __shfl(sq[1], c15, 64);
            const float sg2 = __shfl(sq[2], c15, 64);
            const float sg3 = __shfl(sq[3], c15, 64);
            const float spre = (g < 2) ? (g == 0 ? sg0 : sg1) : (g == 2 ? sg2 : sg3);
            const float sp = fmaxf(spre, 0.f) + log1pf(expf(-fabsf(spre)));
            const float sigma = m ? sp : 0.f;
            const float al = -sigma * dist;

            // ---- inclusive wave scan of alpha_log ----
            float xs = al;
            #pragma unroll
            for (int d = 1; d < 64; d <<= 1) {
                float y = __shfl_up(xs, (unsigned)d, 64);
                if (lane >= d) xs += y;
            }
            const float total = __shfl(xs, 63, 64);
            const float trans = expf(carry + (xs - al));
            const float alpha = 1.0f - expf(al);
            const float w = trans * alpha;
            carry += total;

            const bool m2 = m & (w > 1e-4f);
            if (__ballot(m2)) {
                // ---- color L1: H2^T = relu(Wr1^T [F;dirs]^T + br1) ----
                f16x8 bf[4];
                #pragma unroll
                for (int nt = 0; nt < 4; ++nt)
                    bf[nt] = *(const f16x8*)(ldsH + (16*nt + c15)*ROWP + ((16*g) ^ swc));
                __builtin_amdgcn_s_setprio(1);
                #pragma unroll
                for (int mt = 0; mt < 4; ++mt) {
                    f16x8 a0 = AF[(6 + mt*2 + 0)*64 + lane];
                    f16x8 a1 = AF[(6 + mt*2 + 1)*64 + lane];
                    f32x4 acc[4];
                    #pragma unroll
                    for (int nt = 0; nt < 4; ++nt) { f32x4 z = {0.f,0.f,0.f,0.f}; acc[nt] = z; }
                    #pragma unroll
                    for (int nt = 0; nt < 4; ++nt) acc[nt] = mfma16(a0, bf[nt], acc[nt]);
                    #pragma unroll
                    for (int nt = 0; nt < 4; ++nt) acc[nt] = mfma16(a1, bd, acc[nt]);
                    #pragma unroll
                    for (int nt = 0; nt < 4; ++nt) {
                        u32x2 ww;
                        ww[0] = pkmax0(pkadd(pk2(acc[nt][0], acc[nt][1]), r1pkv[mt][0]));
                        ww[1] = pkmax0(pkadd(pk2(acc[nt][2], acc[nt][3]), r1pkv[mt][1]));
                        *(u32x2*)(ldsH + (16*nt + c15)*ROWP + ((32*mt + 8*g) ^ swc)) = ww;
                    }
                }
                // ---- color L2: RGB^T = Wr2^T H2^T ----
                f16x8 a0 = AF[14*64 + lane];
                f16x8 a1 = AF[15*64 + lane];
                f32x4 accr[4];
                #pragma unroll
                for (int nt = 0; nt < 4; ++nt) {
                    f16x8 q0c = *(const f16x8*)(ldsH + (16*nt + c15)*ROWP + ((16*g) ^ swc));
                    f16x8 q1c = *(const f16x8*)(ldsH + (16*nt + c15)*ROWP + ((64 + 16*g) ^ swc));
                    f32x4 z = {0.f,0.f,0.f,0.f};
                    z = mfma16(a0, q0c, z);
                    z = mfma16(a1, q1c, z);
                    accr[nt] = z;
                }
                __builtin_amdgcn_s_setprio(0);
                // rgb broadcast via shuffles (rows 0..2 of tile s>>4, col s&15)
                float t0, t1, t2, t3, l0, l1, l2;
                t0 = __shfl(accr[0][0], c15, 64); t1 = __shfl(accr[1][0], c15, 64);
                t2 = __shfl(accr[2][0], c15, 64); t3 = __shfl(accr[3][0], c15, 64);
                l0 = ((g < 2) ? (g == 0 ? t0 : t1) : (g == 2 ? t2 : t3)) + c0b;
                t0 = __shfl(accr[0][1], c15, 64); t1 = __shfl(accr[1][1], c15, 64);
                t2 = __shfl(accr[2][1], c15, 64); t3 = __shfl(accr[3][1], c15, 64);
                l1 = ((g < 2) ? (g == 0 ? t0 : t1) : (g == 2 ? t2 : t3)) + c1b;
                t0 = __shfl(accr[0][2], c15, 64); t1 = __shfl(accr[1][2], c15, 64);
                t2 = __shfl(accr[2][2], c15, 64); t3 = __shfl(accr[3][2], c15, 64);
                l2 = ((g < 2) ? (g == 0 ? t0 : t1) : (g == 2 ? t2 : t3)) + c2b;

                const float wm = m2 ? w : 0.f;
                rr = fmaf(1.f/(1.f + expf(-l0)), wm, rr);
                rg = fmaf(1.f/(1.f + expf(-l1)), wm, rg);
                rb = fmaf(1.f/(1.f + expf(-l2)), wm, rb);
            }
            // early termination: carry <= ln(5e-5)  (exp-free compare)
            if (chunk == 0 && carry <= -9.9034875f) break;
        }
    }

    #pragma unroll
    for (int d = 32; d > 0; d >>= 1) {
        rr += __shfl_xor(rr, d, 64);
        rg += __shfl_xor(rg, d, 64);
        rb += __shfl_xor(rb, d, 64);
    }
    if (lane == 0) {
        out[ray*3+0] = rr;
        out[ray*3+1] = rg;
        out[ray*3+2] = rb;
    }
}

extern "C" void kernel_launch(void* const* d_in, const int* in_sizes, int n_in,
                              void* d_out, int out_size, void* d_ws, size_t ws_size,
                              hipStream_t stream) {
    const float* rays_o = (const float*)d_in[0];
    const float* rays_d = (const float*)d_in[1];
    const float* grid   = (const float*)d_in[2];
    const float* W1  = (const float*)d_in[3];
    const float* b1  = (const float*)d_in[4];
    const float* W2  = (const float*)d_in[5];
    const float* b2  = (const float*)d_in[6];
    const float* Ws  = (const float*)d_in[7];
    const float* bs  = (const float*)d_in[8];
    const float* Wr1 = (const float*)d_in[9];
    const float* br1 = (const float*)d_in[10];
    const float* Wr2 = (const float*)d_in[11];
    const float* br2 = (const float*)d_in[12];
    float* out = (float*)d_out;
    unsigned char* ws = (unsigned char*)d_ws;

    prep<<<dim3(1), dim3(1024), 0, stream>>>(W1, b1, W2, b2, Ws, bs, Wr1, br1, Wr2, ws);
    nerf_render<<<dim3(16384), dim3(64), 0, stream>>>(
        rays_o, rays_d, grid, br2, ws, out);
}